// Round 6
// baseline (258.449 us; speedup 1.0000x reference)
//
#include <hip/hip_runtime.h>
#include <hip/hip_bf16.h>

// B=4, N=4096, C=F=128.  out = softmax(QK^T) V + x.
// R6: (a) attn loads were serialized ~4-deep (VGPR 80) -> batch all 16 K-frag
// loads before QK and all 16 V-frag loads before exp (launch_bounds(128,2),
// ~210 VGPR); split-4, 1024 blocks = 4 blocks/CU, 8 waves/CU.  (b) collapse
// 4 dispatches -> 2: W hi/lo gathered per-lane from global inside qkv (no
// wprep), combine fused into attn via threadfence+atomic last-block merge.

#define TOKENS 16384
#define NSEQ   4096
#define DIM    128
#define SPLITS 4
#define JSPL   16            // 64 key-tiles / 4 splits

using bf16x8  = __attribute__((ext_vector_type(8))) __bf16;
using f16x8   = __attribute__((ext_vector_type(8))) _Float16;
using floatx4 = __attribute__((ext_vector_type(4))) float;

__device__ __forceinline__ unsigned short f2bf(float f) {
  unsigned u = __float_as_uint(f);
  u += 0x7FFFu + ((u >> 16) & 1u);   // round-to-nearest-even
  return (unsigned short)(u >> 16);
}
__device__ __forceinline__ float bf2f(unsigned short h) {
  return __uint_as_float(((unsigned)h) << 16);
}
__device__ __forceinline__ unsigned short f2h(float f) {
  union { _Float16 h; unsigned short s; } u;
  u.h = (_Float16)f;
  return u.s;
}

// Fragment layouts in workspace (frag = 64 lanes x 8 shorts = 512 shorts):
//   KF[b][j(64)][nt(4)][kt(4)][lane][8] : K[n=nt*16+l16][k=kt*32+quad*8+e], fp16
//   VF[b][j(64)][nt(8)][kt(2)][lane][8] : V[key=kt*32+quad*8+e][d=nt*16+l16], bf16

// ---------------------------------------------------------------------------
// Kernel 1: QKV projection as MFMA GEMM, bf16 hi/lo 3-pass (fp32-accurate).
// Grid (6,128): x = 64-col slice (matrix-uniform), y = 128-token tile, 4 waves.
// W B-frags gathered per-lane straight from global fp32 (64KB slice, L2/L3-hot,
// redundant across waves but cheap) and hi/lo split in registers.
// Outputs: Q fp16 row-major; K fp16 fragment layout; V bf16 fragment layout.
// ---------------------------------------------------------------------------
__global__ __launch_bounds__(256, 2) void qkv_gemm(
    const float* __restrict__ X,
    const float* __restrict__ Wq, const float* __restrict__ Wk,
    const float* __restrict__ Wv,
    const float* __restrict__ bq, const float* __restrict__ bk,
    const float* __restrict__ bv,
    unsigned short* __restrict__ Qh, unsigned short* __restrict__ KF,
    unsigned short* __restrict__ VF)
{
  __shared__ __align__(16) unsigned short sOut[128 * 72]; // out tile [row][col]

  const int tid  = threadIdx.x;
  const int w    = tid >> 6;
  const int lane = tid & 63;
  const int l16  = lane & 15;
  const int quad = lane >> 4;
  const int n0   = blockIdx.x * 64;
  const int m0b  = blockIdx.y * 128;
  const int m0   = m0b + w * 32;
  const int mat  = n0 >> 7;                      // 0=Q, 1=K, 2=V
  const int fbase = n0 & 127;
  const float* Wsrc = (mat == 0) ? Wq : (mat == 1) ? Wk : Wv;

  // A-fragments from X with in-register hi/lo split.
  bf16x8 xh[2][4], xl[2][4];
#pragma unroll
  for (int mt = 0; mt < 2; ++mt) {
    const float* xp = X + (size_t)(m0 + mt * 16 + l16) * 128 + quad * 8;
#pragma unroll
    for (int kt = 0; kt < 4; ++kt) {
      const float4 a = *reinterpret_cast<const float4*>(xp + kt * 32);
      const float4 c = *reinterpret_cast<const float4*>(xp + kt * 32 + 4);
      union { bf16x8 v; unsigned short s[8]; } uh, ul;
      const float xs[8] = {a.x, a.y, a.z, a.w, c.x, c.y, c.z, c.w};
#pragma unroll
      for (int e = 0; e < 8; ++e) {
        const unsigned short hs = f2bf(xs[e]);
        uh.s[e] = hs;
        ul.s[e] = f2bf(xs[e] - bf2f(hs));
      }
      xh[mt][kt] = uh.v;
      xl[mt][kt] = ul.v;
    }
  }

  floatx4 acc[2][4];
#pragma unroll
  for (int mt = 0; mt < 2; ++mt)
#pragma unroll
    for (int nt = 0; nt < 4; ++nt) acc[mt][nt] = (floatx4)(0.0f);

  // C = Xh*Wh + Xl*Wh + Xh*Wl (lo*lo dropped). W gathered per nt from global:
  // B-frag element (n=nt*16+l16, k=kt*32+quad*8+e) = W[k][fbase+n].
#pragma unroll
  for (int nt = 0; nt < 4; ++nt) {
    bf16x8 bh[4], bl[4];
#pragma unroll
    for (int kt = 0; kt < 4; ++kt) {
      union { bf16x8 v; unsigned short s[8]; } uh, ul;
#pragma unroll
      for (int e = 0; e < 8; ++e) {
        const float wv = Wsrc[(size_t)(kt * 32 + quad * 8 + e) * 128 +
                              fbase + nt * 16 + l16];
        const unsigned short hs = f2bf(wv);
        uh.s[e] = hs;
        ul.s[e] = f2bf(wv - bf2f(hs));
      }
      bh[kt] = uh.v;
      bl[kt] = ul.v;
    }
#pragma unroll
    for (int kt = 0; kt < 4; ++kt)
#pragma unroll
      for (int mt = 0; mt < 2; ++mt) {
        acc[mt][nt] = __builtin_amdgcn_mfma_f32_16x16x32_bf16(xh[mt][kt], bh[kt], acc[mt][nt], 0, 0, 0);
        acc[mt][nt] = __builtin_amdgcn_mfma_f32_16x16x32_bf16(xl[mt][kt], bh[kt], acc[mt][nt], 0, 0, 0);
        acc[mt][nt] = __builtin_amdgcn_mfma_f32_16x16x32_bf16(xh[mt][kt], bl[kt], acc[mt][nt], 0, 0, 0);
      }
  }

  // --- Epilogue: bias + convert -> sOut [128 rows][72 pad shorts] ---
  const float* bias_p = (mat == 0) ? bq : (mat == 1) ? bk : bv;
  float bias[4];
#pragma unroll
  for (int nt = 0; nt < 4; ++nt) bias[nt] = bias_p[fbase + nt * 16 + l16];

#pragma unroll
  for (int mt = 0; mt < 2; ++mt)
#pragma unroll
    for (int nt = 0; nt < 4; ++nt)
#pragma unroll
      for (int r = 0; r < 4; ++r) {
        const float val = acc[mt][nt][r] + bias[nt];
        sOut[(w * 32 + mt * 16 + quad * 4 + r) * 72 + nt * 16 + l16] =
            (mat == 2) ? f2bf(val) : f2h(val);
      }
  __syncthreads();

  // --- Store phase: 1024 x 16-B dest-contiguous chunks, 4/thread ---
  if (mat == 0) {
#pragma unroll
    for (int i = 0; i < 4; ++i) {
      const int c = i * 256 + tid, row = c >> 3, c8 = c & 7;
      *reinterpret_cast<uint4*>(Qh + (size_t)(m0b + row) * DIM + fbase + c8 * 8) =
          *reinterpret_cast<const uint4*>(&sOut[row * 72 + c8 * 8]);
    }
  } else if (mat == 1) {
#pragma unroll
    for (int i = 0; i < 4; ++i) {
      const int c = i * 256 + tid, row = c >> 3, c8 = c & 7;
      const int token = m0b + row;
      const int bK = token >> 12, j = (token & (NSEQ - 1)) >> 6, nl = token & 63;
      const int nt = nl >> 4, lk = nl & 15;
      const int feat = fbase + c8 * 8;
      const int kt = feat >> 5, qd = (feat >> 3) & 3;
      const size_t addr =
          ((((size_t)(bK * 64 + j) * 4 + nt) * 4 + kt) * 64 + qd * 16 + lk) * 8;
      *reinterpret_cast<uint4*>(KF + addr) =
          *reinterpret_cast<const uint4*>(&sOut[row * 72 + c8 * 8]);
    }
  } else {
#pragma unroll
    for (int i = 0; i < 4; ++i) {
      const int c = i * 256 + tid;
      const int d_loc = c & 63, key8 = c >> 6;
      const int d = fbase + d_loc, nt = d >> 4, lv = d & 15;
      const int k7 = key8 & 7, kt = k7 >> 2, qd = k7 & 3;
      const int token0 = m0b + key8 * 8;
      const int bV = token0 >> 12, j = (token0 & (NSEQ - 1)) >> 6;
      unsigned short tmp[8];
#pragma unroll
      for (int e = 0; e < 8; ++e) tmp[e] = sOut[(key8 * 8 + e) * 72 + d_loc];
      const size_t addr =
          ((((size_t)(bV * 64 + j) * 8 + nt) * 2 + kt) * 64 + qd * 16 + lv) * 8;
      *reinterpret_cast<uint4*>(VF + addr) = *reinterpret_cast<const uint4*>(tmp);
    }
  }
}

// ---------------------------------------------------------------------------
// Kernel 2: flash attention quarter + fused combine. 1024 blocks x 128 thr
// (2 waves, M=32/wave). All 16 K loads batched before QK; all 16 V loads
// batched before exp (latency hidden under softmax). Last block per (b,qtile)
// merges the 4 split results + residual (threadfence + device atomics).
// ---------------------------------------------------------------------------
__global__ __launch_bounds__(128, 2) void attn(
    const unsigned short* __restrict__ Qh, const unsigned short* __restrict__ KF,
    const unsigned short* __restrict__ VF, const float* __restrict__ X,
    unsigned short* __restrict__ Opart, float* __restrict__ Lpart,
    int* __restrict__ ctr, float* __restrict__ Out)
{
  __shared__ __align__(16) unsigned short sP[2 * 32 * 72];  // per-wave P
  __shared__ float sWt[SPLITS * 64];
  __shared__ int sFlag;

  const int tid  = threadIdx.x;
  const int w    = tid >> 6;
  const int lane = tid & 63;
  const int l16  = lane & 15;
  const int quad = lane >> 4;
  const int b    = blockIdx.x >> 8;
  const int sp   = (blockIdx.x >> 6) & 3;
  const int qt   = blockIdx.x & 63;
  const int q0   = qt * 64;

  unsigned short* sPw = &sP[w * 32 * 72];

  // Q A-frags (fp16): A[m=l16][k=quad*8+e], rows w*32 + mt*16 + l16.
  f16x8 aq[2][4];
#pragma unroll
  for (int mt = 0; mt < 2; ++mt) {
    const unsigned short* qp =
        Qh + (size_t)(b * NSEQ + q0 + w * 32 + mt * 16 + l16) * DIM + quad * 8;
#pragma unroll
    for (int kt = 0; kt < 4; ++kt)
      aq[mt][kt] = *reinterpret_cast<const f16x8*>(qp + kt * 32);
  }

  floatx4 o[2][8];
#pragma unroll
  for (int mt = 0; mt < 2; ++mt)
#pragma unroll
    for (int nt = 0; nt < 8; ++nt) o[mt][nt] = (floatx4)(0.0f);
  float l_part[2][4] = {{0, 0, 0, 0}, {0, 0, 0, 0}};

  for (int j = sp * JSPL; j < sp * JSPL + JSPL; ++j) {
    const unsigned short* kf = KF + (size_t)(b * 64 + j) * 8192 + lane * 8;
    const unsigned short* vf = VF + (size_t)(b * 64 + j) * 8192 + lane * 8;

    // Batch ALL 16 K-frag loads (64 VGPRs in flight).
    f16x8 bk[4][4];
#pragma unroll
    for (int nt = 0; nt < 4; ++nt)
#pragma unroll
      for (int kt = 0; kt < 4; ++kt)
        bk[nt][kt] = *reinterpret_cast<const f16x8*>(kf + nt * 2048 + kt * 512);

    // S = Q K^T (fp16).
    floatx4 s[2][4];
#pragma unroll
    for (int mt = 0; mt < 2; ++mt)
#pragma unroll
      for (int nt = 0; nt < 4; ++nt) s[mt][nt] = (floatx4)(0.0f);
#pragma unroll
    for (int nt = 0; nt < 4; ++nt)
#pragma unroll
      for (int kt = 0; kt < 4; ++kt)
#pragma unroll
        for (int mt = 0; mt < 2; ++mt)
          s[mt][nt] = __builtin_amdgcn_mfma_f32_16x16x32_f16(aq[mt][kt], bk[nt][kt], s[mt][nt], 0, 0, 0);

    // Batch ALL 16 V-frag loads now; latency hides under exp below.
    bf16x8 bv[8][2];
#pragma unroll
    for (int nt = 0; nt < 8; ++nt)
#pragma unroll
      for (int kt = 0; kt < 2; ++kt)
        bv[nt][kt] = *reinterpret_cast<const bf16x8*>(vf + nt * 1024 + kt * 512);

    // No-max softmax (logits bounded ~70 < fp32 exp limit); P bf16 (range).
#pragma unroll
    for (int mt = 0; mt < 2; ++mt)
#pragma unroll
      for (int nt = 0; nt < 4; ++nt)
#pragma unroll
        for (int r = 0; r < 4; ++r) {
          const float p = __expf(s[mt][nt][r]);
          l_part[mt][r] += p;
          sPw[(mt * 16 + quad * 4 + r) * 72 + nt * 16 + l16] = f2bf(p);
        }

    // P A-frags from wave-private LDS (no barrier).
    bf16x8 ap[2][2];
#pragma unroll
    for (int mt = 0; mt < 2; ++mt)
#pragma unroll
      for (int kt = 0; kt < 2; ++kt)
        ap[mt][kt] = *reinterpret_cast<const bf16x8*>(
            &sPw[(mt * 16 + l16) * 72 + kt * 32 + quad * 8]);

    // O += P V (bf16).
#pragma unroll
    for (int nt = 0; nt < 8; ++nt)
#pragma unroll
      for (int kt = 0; kt < 2; ++kt)
#pragma unroll
        for (int mt = 0; mt < 2; ++mt)
          o[mt][nt] = __builtin_amdgcn_mfma_f32_16x16x32_bf16(ap[mt][kt], bv[nt][kt], o[mt][nt], 0, 0, 0);
  }

  // Partial epilogue: reduce l over 16 cols, store normalized bf16 O + l.
#pragma unroll
  for (int mt = 0; mt < 2; ++mt)
#pragma unroll
    for (int r = 0; r < 4; ++r) {
      float l = l_part[mt][r];
      l += __shfl_xor(l, 1);
      l += __shfl_xor(l, 2);
      l += __shfl_xor(l, 4);
      l += __shfl_xor(l, 8);
      const float inv = 1.0f / l;
      const int t = q0 + w * 32 + mt * 16 + quad * 4 + r;
      const size_t ob = ((size_t)sp * TOKENS + b * NSEQ + t) * DIM;
#pragma unroll
      for (int nt = 0; nt < 8; ++nt)
        Opart[ob + nt * 16 + l16] = f2bf(o[mt][nt][r] * inv);
      if (l16 == 0) Lpart[sp * TOKENS + b * NSEQ + t] = l;
    }

  // --- Fused combine: last block of the 4 splits merges + residual ---
  __threadfence();          // release our Opart/Lpart stores (device scope)
  __syncthreads();
  if (tid == 0)
    sFlag = (atomicAdd(&ctr[b * 64 + qt], 1) == SPLITS - 1);
  __syncthreads();
  if (!sFlag) return;
  __threadfence();          // acquire: other splits' stores now visible

  if (tid < 64) {
    const int t = b * NSEQ + q0 + tid;
    float ls[SPLITS], tot = 0.0f;
#pragma unroll
    for (int s = 0; s < SPLITS; ++s) { ls[s] = Lpart[s * TOKENS + t]; tot += ls[s]; }
    const float winv = 1.0f / tot;
#pragma unroll
    for (int s = 0; s < SPLITS; ++s) sWt[s * 64 + tid] = ls[s] * winv;
  }
  __syncthreads();

#pragma unroll
  for (int i = 0; i < 8; ++i) {
    const int c = i * 128 + tid;            // 1024 chunks of 8 floats
    const int row = c >> 4, cg = (c & 15) * 8;
    const size_t base = (size_t)(b * NSEQ + q0 + row) * DIM + cg;
    const float4 x0 = *reinterpret_cast<const float4*>(X + base);
    const float4 x1 = *reinterpret_cast<const float4*>(X + base + 4);
    float os[8] = {x0.x, x0.y, x0.z, x0.w, x1.x, x1.y, x1.z, x1.w};
#pragma unroll
    for (int s = 0; s < SPLITS; ++s) {
      const float ws = sWt[s * 64 + row];
      const uint4 u = *reinterpret_cast<const uint4*>(
          Opart + (size_t)s * TOKENS * DIM + base);
      const unsigned uu[4] = {u.x, u.y, u.z, u.w};
#pragma unroll
      for (int e = 0; e < 4; ++e) {
        os[2 * e]     += ws * bf2f(uu[e] & 0xffff);
        os[2 * e + 1] += ws * bf2f(uu[e] >> 16);
      }
    }
    float4 o0 = {os[0], os[1], os[2], os[3]};
    float4 o1 = {os[4], os[5], os[6], os[7]};
    *reinterpret_cast<float4*>(Out + base)     = o0;
    *reinterpret_cast<float4*>(Out + base + 4) = o1;
  }
}

// ---------------------------------------------------------------------------
extern "C" void kernel_launch(void* const* d_in, const int* in_sizes, int n_in,
                              void* d_out, int out_size, void* d_ws, size_t ws_size,
                              hipStream_t stream) {
  const float* X  = (const float*)d_in[0];
  const float* Wq = (const float*)d_in[1];
  const float* bq = (const float*)d_in[2];
  const float* Wk = (const float*)d_in[3];
  const float* bk = (const float*)d_in[4];
  const float* Wv = (const float*)d_in[5];
  const float* bv = (const float*)d_in[6];
  float* Out = (float*)d_out;

  const size_t MAT = (size_t)TOKENS * DIM;   // 2 M elements
  unsigned short* Qh    = (unsigned short*)d_ws;          // fp16 row-major, 4MB
  unsigned short* KF    = Qh + MAT;                       // fp16 frag, 4MB
  unsigned short* VF    = KF + MAT;                       // bf16 frag, 4MB
  unsigned short* Opart = VF + MAT;                       // bf16, SPLITS x 4MB
  float*          Lpart = (float*)(Opart + (size_t)SPLITS * MAT);
  int*            ctr   = (int*)(Lpart + (size_t)SPLITS * TOKENS);
  // total ws ~ 28.3 MB

  hipMemsetAsync(ctr, 0, 256 * sizeof(int), stream);
  qkv_gemm<<<dim3(6, 128), 256, 0, stream>>>(X, Wq, Wk, Wv, bq, bk, bv,
                                             Qh, KF, VF);
  attn<<<4 * SPLITS * 64, 128, 0, stream>>>(Qh, KF, VF, X, Opart, Lpart,
                                            ctr, Out);
}

// Round 7
// 169.219 us; speedup vs baseline: 1.5273x; 1.5273x over previous
//
#include <hip/hip_runtime.h>
#include <hip/hip_bf16.h>

// B=4, N=4096, C=F=128.  out = softmax(QK^T) V + x.
// R7: revert R6's fused combine (device-scope threadfence forced L2 writebacks:
// WRITE_SIZE 12.5->26.4 MB, attn 96.7->180 us). Keep R5 structure and fix its
// real limiter (serialized L2 loads at 1.5 waves/SIMD): software pipeline --
// V-frag loads issued before QK (consumed last), K(j+1) prefetched during
// exp/PV(j) -- plus split-4 grid (1024 blocks = 4 blocks/CU x 2 waves = 8
// waves/CU, matching the 2-waves/SIMD VGPR ceiling).

#define TOKENS 16384
#define NSEQ   4096
#define DIM    128
#define SPLITS 4
#define JSPL   16            // 64 key-tiles / 4 splits

using bf16x8  = __attribute__((ext_vector_type(8))) __bf16;
using f16x8   = __attribute__((ext_vector_type(8))) _Float16;
using floatx4 = __attribute__((ext_vector_type(4))) float;

__device__ __forceinline__ unsigned short f2bf(float f) {
  unsigned u = __float_as_uint(f);
  u += 0x7FFFu + ((u >> 16) & 1u);   // round-to-nearest-even
  return (unsigned short)(u >> 16);
}
__device__ __forceinline__ float bf2f(unsigned short h) {
  return __uint_as_float(((unsigned)h) << 16);
}
__device__ __forceinline__ unsigned short f2h(float f) {
  union { _Float16 h; unsigned short s; } u;
  u.h = (_Float16)f;
  return u.s;
}

// Fragment layouts in workspace (frag = 64 lanes x 8 shorts = 512 shorts):
//   KF[b][j(64)][nt(4)][kt(4)][lane][8] : K[n=nt*16+l16][k=kt*32+quad*8+e], fp16
//   VF[b][j(64)][nt(8)][kt(2)][lane][8] : V[key=kt*32+quad*8+e][d=nt*16+l16], bf16

// ---------------------------------------------------------------------------
// Kernel 0: transpose + hi/lo split W -> Wt[n][k], n in [0,384): Q|K|V.
// ---------------------------------------------------------------------------
__global__ __launch_bounds__(384) void wprep(
    const float* __restrict__ Wq, const float* __restrict__ Wk,
    const float* __restrict__ Wv,
    unsigned short* __restrict__ Wth, unsigned short* __restrict__ Wtl)
{
  const int k = blockIdx.x;        // 0..127
  const int n = threadIdx.x;       // 0..383
  const float* W = (n < 128) ? Wq : (n < 256) ? Wk : Wv;
  const float wv = W[k * 128 + (n & 127)];
  const unsigned short h = f2bf(wv);
  Wth[n * 128 + k] = h;
  Wtl[n * 128 + k] = f2bf(wv - bf2f(h));
}

// ---------------------------------------------------------------------------
// Kernel 1: QKV projection as MFMA GEMM, bf16 hi/lo 3-pass (fp32-accurate).
// Grid (6,128): x = 64-col slice (matrix-uniform), y = 128-token tile.
// Epilogue: acc -> LDS (padded) -> dest-contiguous b128 stores.
// Outputs: Q fp16 row-major; K fp16 fragment layout; V bf16 fragment layout.
// ---------------------------------------------------------------------------
__global__ __launch_bounds__(256) void qkv_gemm(
    const float* __restrict__ X,
    const unsigned short* __restrict__ Wth, const unsigned short* __restrict__ Wtl,
    const float* __restrict__ bq, const float* __restrict__ bk,
    const float* __restrict__ bv,
    unsigned short* __restrict__ Qh, unsigned short* __restrict__ KF,
    unsigned short* __restrict__ VF)
{
  __shared__ __align__(16) unsigned short sWh[64 * 136];  // W^T slice hi [n][k]
  __shared__ __align__(16) unsigned short sWl[64 * 136];  // W^T slice lo [n][k]
  __shared__ __align__(16) unsigned short sOut[128 * 72]; // out tile [row][col]

  const int tid  = threadIdx.x;
  const int w    = tid >> 6;
  const int lane = tid & 63;
  const int l16  = lane & 15;
  const int quad = lane >> 4;
  const int n0   = blockIdx.x * 64;
  const int m0b  = blockIdx.y * 128;
  const int m0   = m0b + w * 32;

  // Stage W^T slice hi+lo, coalesced b128.
#pragma unroll
  for (int i = 0; i < 4; ++i) {
    const int c = i * 256 + tid;
    const int row = c >> 4, col8 = c & 15;
    *reinterpret_cast<uint4*>(&sWh[row * 136 + col8 * 8]) =
        *reinterpret_cast<const uint4*>(Wth + (n0 + row) * 128 + col8 * 8);
    *reinterpret_cast<uint4*>(&sWl[row * 136 + col8 * 8]) =
        *reinterpret_cast<const uint4*>(Wtl + (n0 + row) * 128 + col8 * 8);
  }

  // A-fragments from X with in-register hi/lo split.
  bf16x8 xh[2][4], xl[2][4];
#pragma unroll
  for (int mt = 0; mt < 2; ++mt) {
    const float* xp = X + (size_t)(m0 + mt * 16 + l16) * 128 + quad * 8;
#pragma unroll
    for (int kt = 0; kt < 4; ++kt) {
      const float4 a = *reinterpret_cast<const float4*>(xp + kt * 32);
      const float4 c = *reinterpret_cast<const float4*>(xp + kt * 32 + 4);
      union { bf16x8 v; unsigned short s[8]; } uh, ul;
      const float xs[8] = {a.x, a.y, a.z, a.w, c.x, c.y, c.z, c.w};
#pragma unroll
      for (int e = 0; e < 8; ++e) {
        const unsigned short hs = f2bf(xs[e]);
        uh.s[e] = hs;
        ul.s[e] = f2bf(xs[e] - bf2f(hs));
      }
      xh[mt][kt] = uh.v;
      xl[mt][kt] = ul.v;
    }
  }
  __syncthreads();

  floatx4 acc[2][4];
#pragma unroll
  for (int mt = 0; mt < 2; ++mt)
#pragma unroll
    for (int nt = 0; nt < 4; ++nt) acc[mt][nt] = (floatx4)(0.0f);

  // C = Xh*Wh + Xl*Wh + Xh*Wl  (lo*lo dropped).
#pragma unroll
  for (int nt = 0; nt < 4; ++nt) {
#pragma unroll
    for (int kt = 0; kt < 4; ++kt) {
      const int off = (nt * 16 + l16) * 136 + kt * 32 + quad * 8;
      const bf16x8 bh = *reinterpret_cast<const bf16x8*>(&sWh[off]);
      const bf16x8 bl = *reinterpret_cast<const bf16x8*>(&sWl[off]);
#pragma unroll
      for (int mt = 0; mt < 2; ++mt) {
        acc[mt][nt] = __builtin_amdgcn_mfma_f32_16x16x32_bf16(xh[mt][kt], bh, acc[mt][nt], 0, 0, 0);
        acc[mt][nt] = __builtin_amdgcn_mfma_f32_16x16x32_bf16(xl[mt][kt], bh, acc[mt][nt], 0, 0, 0);
        acc[mt][nt] = __builtin_amdgcn_mfma_f32_16x16x32_bf16(xh[mt][kt], bl, acc[mt][nt], 0, 0, 0);
      }
    }
  }

  // --- Epilogue: bias + convert -> sOut [128 rows][72 pad shorts] ---
  const int mat = n0 >> 7;                      // 0=Q, 1=K, 2=V
  const float* bias_p = (mat == 0) ? bq : (mat == 1) ? bk : bv;
  const int fbase = n0 & 127;
  float bias[4];
#pragma unroll
  for (int nt = 0; nt < 4; ++nt) bias[nt] = bias_p[fbase + nt * 16 + l16];

#pragma unroll
  for (int mt = 0; mt < 2; ++mt)
#pragma unroll
    for (int nt = 0; nt < 4; ++nt)
#pragma unroll
      for (int r = 0; r < 4; ++r) {
        const float val = acc[mt][nt][r] + bias[nt];
        sOut[(w * 32 + mt * 16 + quad * 4 + r) * 72 + nt * 16 + l16] =
            (mat == 2) ? f2bf(val) : f2h(val);
      }
  __syncthreads();

  // --- Store phase: 1024 x 16-B dest-contiguous chunks, 4/thread ---
  if (mat == 0) {
#pragma unroll
    for (int i = 0; i < 4; ++i) {
      const int c = i * 256 + tid, row = c >> 3, c8 = c & 7;
      *reinterpret_cast<uint4*>(Qh + (size_t)(m0b + row) * DIM + fbase + c8 * 8) =
          *reinterpret_cast<const uint4*>(&sOut[row * 72 + c8 * 8]);
    }
  } else if (mat == 1) {
#pragma unroll
    for (int i = 0; i < 4; ++i) {
      const int c = i * 256 + tid, row = c >> 3, c8 = c & 7;
      const int token = m0b + row;
      const int bK = token >> 12, j = (token & (NSEQ - 1)) >> 6, nl = token & 63;
      const int nt = nl >> 4, lk = nl & 15;
      const int feat = fbase + c8 * 8;
      const int kt = feat >> 5, qd = (feat >> 3) & 3;
      const size_t addr =
          ((((size_t)(bK * 64 + j) * 4 + nt) * 4 + kt) * 64 + qd * 16 + lk) * 8;
      *reinterpret_cast<uint4*>(KF + addr) =
          *reinterpret_cast<const uint4*>(&sOut[row * 72 + c8 * 8]);
    }
  } else {
#pragma unroll
    for (int i = 0; i < 4; ++i) {
      const int c = i * 256 + tid;
      const int d_loc = c & 63, key8 = c >> 6;
      const int d = fbase + d_loc, nt = d >> 4, lv = d & 15;
      const int k7 = key8 & 7, kt = k7 >> 2, qd = k7 & 3;
      const int token0 = m0b + key8 * 8;
      const int bV = token0 >> 12, j = (token0 & (NSEQ - 1)) >> 6;
      unsigned short tmp[8];
#pragma unroll
      for (int e = 0; e < 8; ++e) tmp[e] = sOut[(key8 * 8 + e) * 72 + d_loc];
      const size_t addr =
          ((((size_t)(bV * 64 + j) * 8 + nt) * 2 + kt) * 64 + qd * 16 + lv) * 8;
      *reinterpret_cast<uint4*>(VF + addr) = *reinterpret_cast<const uint4*>(tmp);
    }
  }
}

// ---------------------------------------------------------------------------
// Kernel 2: flash attention quarter, software-pipelined. 1024 blocks x 128
// threads (2 waves, M=32/wave). Per iter: V(j) loads issued first (consumed
// last), QK with pre-loaded K(j), K(j+1) prefetch, exp/P, PV. No barriers.
// ---------------------------------------------------------------------------
__global__ __launch_bounds__(128, 2) void attn(
    const unsigned short* __restrict__ Qh, const unsigned short* __restrict__ KF,
    const unsigned short* __restrict__ VF,
    unsigned short* __restrict__ Opart, float* __restrict__ Lpart)
{
  __shared__ __align__(16) unsigned short sP[2 * 32 * 72];  // per-wave P

  const int tid  = threadIdx.x;
  const int w    = tid >> 6;
  const int lane = tid & 63;
  const int l16  = lane & 15;
  const int quad = lane >> 4;
  const int b    = blockIdx.x >> 8;
  const int sp   = (blockIdx.x >> 6) & 3;
  const int qt   = blockIdx.x & 63;
  const int q0   = qt * 64;
  const int j0   = sp * JSPL, j1 = j0 + JSPL;

  unsigned short* sPw = &sP[w * 32 * 72];

  // Q A-frags (fp16): A[m=l16][k=quad*8+e], rows w*32 + mt*16 + l16.
  f16x8 aq[2][4];
#pragma unroll
  for (int mt = 0; mt < 2; ++mt) {
    const unsigned short* qp =
        Qh + (size_t)(b * NSEQ + q0 + w * 32 + mt * 16 + l16) * DIM + quad * 8;
#pragma unroll
    for (int kt = 0; kt < 4; ++kt)
      aq[mt][kt] = *reinterpret_cast<const f16x8*>(qp + kt * 32);
  }

  floatx4 o[2][8];
#pragma unroll
  for (int mt = 0; mt < 2; ++mt)
#pragma unroll
    for (int nt = 0; nt < 8; ++nt) o[mt][nt] = (floatx4)(0.0f);
  float l_part[2][4] = {{0, 0, 0, 0}, {0, 0, 0, 0}};

  // Prologue: K(j0) frags into registers.
  f16x8 bk[4][4];
  {
    const unsigned short* kf = KF + (size_t)(b * 64 + j0) * 8192 + lane * 8;
#pragma unroll
    for (int nt = 0; nt < 4; ++nt)
#pragma unroll
      for (int kt = 0; kt < 4; ++kt)
        bk[nt][kt] = *reinterpret_cast<const f16x8*>(kf + nt * 2048 + kt * 512);
  }

  for (int j = j0; j < j1; ++j) {
    // V(j) loads first: consumed at the very end of the iter (~600 cyc away).
    const unsigned short* vf = VF + (size_t)(b * 64 + j) * 8192 + lane * 8;
    bf16x8 bv[8][2];
#pragma unroll
    for (int nt = 0; nt < 8; ++nt)
#pragma unroll
      for (int kt = 0; kt < 2; ++kt)
        bv[nt][kt] = *reinterpret_cast<const bf16x8*>(vf + nt * 1024 + kt * 512);

    // S = Q K^T with pre-loaded K(j).
    floatx4 s[2][4];
#pragma unroll
    for (int mt = 0; mt < 2; ++mt)
#pragma unroll
      for (int nt = 0; nt < 4; ++nt) s[mt][nt] = (floatx4)(0.0f);
#pragma unroll
    for (int nt = 0; nt < 4; ++nt)
#pragma unroll
      for (int kt = 0; kt < 4; ++kt)
#pragma unroll
        for (int mt = 0; mt < 2; ++mt)
          s[mt][nt] = __builtin_amdgcn_mfma_f32_16x16x32_f16(aq[mt][kt], bk[nt][kt], s[mt][nt], 0, 0, 0);

    // Prefetch K(j+1) — lands during exp/PV below.
    if (j + 1 < j1) {
      const unsigned short* kf = KF + (size_t)(b * 64 + j + 1) * 8192 + lane * 8;
#pragma unroll
      for (int nt = 0; nt < 4; ++nt)
#pragma unroll
        for (int kt = 0; kt < 4; ++kt)
          bk[nt][kt] = *reinterpret_cast<const f16x8*>(kf + nt * 2048 + kt * 512);
    }

    // No-max softmax (logits bounded ~70 < fp32 exp limit); P bf16 (range).
#pragma unroll
    for (int mt = 0; mt < 2; ++mt)
#pragma unroll
      for (int nt = 0; nt < 4; ++nt)
#pragma unroll
        for (int r = 0; r < 4; ++r) {
          const float p = __expf(s[mt][nt][r]);
          l_part[mt][r] += p;
          sPw[(mt * 16 + quad * 4 + r) * 72 + nt * 16 + l16] = f2bf(p);
        }

    // P A-frags from wave-private LDS (no barrier).
    bf16x8 ap[2][2];
#pragma unroll
    for (int mt = 0; mt < 2; ++mt)
#pragma unroll
      for (int kt = 0; kt < 2; ++kt)
        ap[mt][kt] = *reinterpret_cast<const bf16x8*>(
            &sPw[(mt * 16 + l16) * 72 + kt * 32 + quad * 8]);

    // O += P V (bf16), V loaded at iter start.
#pragma unroll
    for (int nt = 0; nt < 8; ++nt)
#pragma unroll
      for (int kt = 0; kt < 2; ++kt)
#pragma unroll
        for (int mt = 0; mt < 2; ++mt)
          o[mt][nt] = __builtin_amdgcn_mfma_f32_16x16x32_bf16(ap[mt][kt], bv[nt][kt], o[mt][nt], 0, 0, 0);
  }

  // Epilogue: reduce l over 16 cols, store normalized bf16 O-part + l-part.
#pragma unroll
  for (int mt = 0; mt < 2; ++mt)
#pragma unroll
    for (int r = 0; r < 4; ++r) {
      float l = l_part[mt][r];
      l += __shfl_xor(l, 1);
      l += __shfl_xor(l, 2);
      l += __shfl_xor(l, 4);
      l += __shfl_xor(l, 8);
      const float inv = 1.0f / l;
      const int t = q0 + w * 32 + mt * 16 + quad * 4 + r;
      const size_t ob = ((size_t)sp * TOKENS + b * NSEQ + t) * DIM;
#pragma unroll
      for (int nt = 0; nt < 8; ++nt)
        Opart[ob + nt * 16 + l16] = f2bf(o[mt][nt][r] * inv);
      if (l16 == 0) Lpart[sp * TOKENS + b * NSEQ + t] = l;
    }
}

// ---------------------------------------------------------------------------
// Kernel 3: combine quarters + residual. out = sum(l_s O_s)/sum(l_s) + x.
// ---------------------------------------------------------------------------
__global__ __launch_bounds__(256) void combine(
    const unsigned short* __restrict__ Opart, const float* __restrict__ Lpart,
    const float* __restrict__ X, float* __restrict__ Out)
{
  const int idx = blockIdx.x * 256 + threadIdx.x;
  const int T   = idx >> 4;
  const int c8  = (idx & 15) * 8;
  float ls[SPLITS], tot = 0.0f;
#pragma unroll
  for (int s = 0; s < SPLITS; ++s) { ls[s] = Lpart[s * TOKENS + T]; tot += ls[s]; }
  const float winv = 1.0f / tot;

  const size_t pa = (size_t)T * DIM + c8;
  const float4 x0 = *reinterpret_cast<const float4*>(X + pa);
  const float4 x1 = *reinterpret_cast<const float4*>(X + pa + 4);
  float os[8] = {x0.x, x0.y, x0.z, x0.w, x1.x, x1.y, x1.z, x1.w};
#pragma unroll
  for (int s = 0; s < SPLITS; ++s) {
    const float ws = ls[s] * winv;
    const uint4 u = *reinterpret_cast<const uint4*>(
        Opart + (size_t)s * TOKENS * DIM + pa);
    const unsigned uu[4] = {u.x, u.y, u.z, u.w};
#pragma unroll
    for (int e = 0; e < 4; ++e) {
      os[2 * e]     += ws * bf2f(uu[e] & 0xffff);
      os[2 * e + 1] += ws * bf2f(uu[e] >> 16);
    }
  }
  float4 o0 = {os[0], os[1], os[2], os[3]};
  float4 o1 = {os[4], os[5], os[6], os[7]};
  *reinterpret_cast<float4*>(Out + pa)     = o0;
  *reinterpret_cast<float4*>(Out + pa + 4) = o1;
}

// ---------------------------------------------------------------------------
extern "C" void kernel_launch(void* const* d_in, const int* in_sizes, int n_in,
                              void* d_out, int out_size, void* d_ws, size_t ws_size,
                              hipStream_t stream) {
  const float* X  = (const float*)d_in[0];
  const float* Wq = (const float*)d_in[1];
  const float* bq = (const float*)d_in[2];
  const float* Wk = (const float*)d_in[3];
  const float* bk = (const float*)d_in[4];
  const float* Wv = (const float*)d_in[5];
  const float* bv = (const float*)d_in[6];
  float* Out = (float*)d_out;

  const size_t MAT = (size_t)TOKENS * DIM;   // 2 M elements
  unsigned short* Qh    = (unsigned short*)d_ws;          // fp16 row-major, 4MB
  unsigned short* KF    = Qh + MAT;                       // fp16 frag, 4MB
  unsigned short* VF    = KF + MAT;                       // bf16 frag, 4MB
  unsigned short* Wth   = VF + MAT;
  unsigned short* Wtl   = Wth + 384 * 128;
  unsigned short* Opart = Wtl + 384 * 128;                // bf16, SPLITS x 4MB
  float*          Lpart = (float*)(Opart + (size_t)SPLITS * MAT);
  // total ws ~ 28.5 MB

  wprep<<<128, 384, 0, stream>>>(Wq, Wk, Wv, Wth, Wtl);
  qkv_gemm<<<dim3(6, 128), 256, 0, stream>>>(X, Wth, Wtl, bq, bk, bv,
                                             Qh, KF, VF);
  attn<<<4 * SPLITS * 64, 128, 0, stream>>>(Qh, KF, VF, Opart, Lpart);
  combine<<<(TOKENS * DIM) / (256 * 8), 256, 0, stream>>>(Opart, Lpart, X, Out);
}

// Round 8
// 157.771 us; speedup vs baseline: 1.6381x; 1.0726x over previous
//
#include <hip/hip_runtime.h>
#include <hip/hip_bf16.h>

// B=4, N=4096, C=F=128.  out = softmax(QK^T) V + x.
// R8: R7's pipeline spilled (live set ~280 VGPR > 256: WRITE_SIZE 64MB of
// scratch). Fit the pipeline to the register budget: batched K(j) at iter
// start, batched V(j) issued right AFTER QK (bk regs recycle into bv),
// NO cross-iter K prefetch. Peak live ~210 VGPR -> zero spill, real
// 2 waves/SIMD. Everything else unchanged from R7.

#define TOKENS 16384
#define NSEQ   4096
#define DIM    128
#define SPLITS 4
#define JSPL   16            // 64 key-tiles / 4 splits

using bf16x8  = __attribute__((ext_vector_type(8))) __bf16;
using f16x8   = __attribute__((ext_vector_type(8))) _Float16;
using floatx4 = __attribute__((ext_vector_type(4))) float;

__device__ __forceinline__ unsigned short f2bf(float f) {
  unsigned u = __float_as_uint(f);
  u += 0x7FFFu + ((u >> 16) & 1u);   // round-to-nearest-even
  return (unsigned short)(u >> 16);
}
__device__ __forceinline__ float bf2f(unsigned short h) {
  return __uint_as_float(((unsigned)h) << 16);
}
__device__ __forceinline__ unsigned short f2h(float f) {
  union { _Float16 h; unsigned short s; } u;
  u.h = (_Float16)f;
  return u.s;
}

// Fragment layouts in workspace (frag = 64 lanes x 8 shorts = 512 shorts):
//   KF[b][j(64)][nt(4)][kt(4)][lane][8] : K[n=nt*16+l16][k=kt*32+quad*8+e], fp16
//   VF[b][j(64)][nt(8)][kt(2)][lane][8] : V[key=kt*32+quad*8+e][d=nt*16+l16], bf16

// ---------------------------------------------------------------------------
// Kernel 0: transpose + hi/lo split W -> Wt[n][k], n in [0,384): Q|K|V.
// ---------------------------------------------------------------------------
__global__ __launch_bounds__(384) void wprep(
    const float* __restrict__ Wq, const float* __restrict__ Wk,
    const float* __restrict__ Wv,
    unsigned short* __restrict__ Wth, unsigned short* __restrict__ Wtl)
{
  const int k = blockIdx.x;        // 0..127
  const int n = threadIdx.x;       // 0..383
  const float* W = (n < 128) ? Wq : (n < 256) ? Wk : Wv;
  const float wv = W[k * 128 + (n & 127)];
  const unsigned short h = f2bf(wv);
  Wth[n * 128 + k] = h;
  Wtl[n * 128 + k] = f2bf(wv - bf2f(h));
}

// ---------------------------------------------------------------------------
// Kernel 1: QKV projection as MFMA GEMM, bf16 hi/lo 3-pass (fp32-accurate).
// Grid (6,128): x = 64-col slice (matrix-uniform), y = 128-token tile.
// Epilogue: acc -> LDS (padded) -> dest-contiguous b128 stores.
// Outputs: Q fp16 row-major; K fp16 fragment layout; V bf16 fragment layout.
// ---------------------------------------------------------------------------
__global__ __launch_bounds__(256) void qkv_gemm(
    const float* __restrict__ X,
    const unsigned short* __restrict__ Wth, const unsigned short* __restrict__ Wtl,
    const float* __restrict__ bq, const float* __restrict__ bk,
    const float* __restrict__ bv,
    unsigned short* __restrict__ Qh, unsigned short* __restrict__ KF,
    unsigned short* __restrict__ VF)
{
  __shared__ __align__(16) unsigned short sWh[64 * 136];  // W^T slice hi [n][k]
  __shared__ __align__(16) unsigned short sWl[64 * 136];  // W^T slice lo [n][k]
  __shared__ __align__(16) unsigned short sOut[128 * 72]; // out tile [row][col]

  const int tid  = threadIdx.x;
  const int w    = tid >> 6;
  const int lane = tid & 63;
  const int l16  = lane & 15;
  const int quad = lane >> 4;
  const int n0   = blockIdx.x * 64;
  const int m0b  = blockIdx.y * 128;
  const int m0   = m0b + w * 32;

  // Stage W^T slice hi+lo, coalesced b128.
#pragma unroll
  for (int i = 0; i < 4; ++i) {
    const int c = i * 256 + tid;
    const int row = c >> 4, col8 = c & 15;
    *reinterpret_cast<uint4*>(&sWh[row * 136 + col8 * 8]) =
        *reinterpret_cast<const uint4*>(Wth + (n0 + row) * 128 + col8 * 8);
    *reinterpret_cast<uint4*>(&sWl[row * 136 + col8 * 8]) =
        *reinterpret_cast<const uint4*>(Wtl + (n0 + row) * 128 + col8 * 8);
  }

  // A-fragments from X with in-register hi/lo split.
  bf16x8 xh[2][4], xl[2][4];
#pragma unroll
  for (int mt = 0; mt < 2; ++mt) {
    const float* xp = X + (size_t)(m0 + mt * 16 + l16) * 128 + quad * 8;
#pragma unroll
    for (int kt = 0; kt < 4; ++kt) {
      const float4 a = *reinterpret_cast<const float4*>(xp + kt * 32);
      const float4 c = *reinterpret_cast<const float4*>(xp + kt * 32 + 4);
      union { bf16x8 v; unsigned short s[8]; } uh, ul;
      const float xs[8] = {a.x, a.y, a.z, a.w, c.x, c.y, c.z, c.w};
#pragma unroll
      for (int e = 0; e < 8; ++e) {
        const unsigned short hs = f2bf(xs[e]);
        uh.s[e] = hs;
        ul.s[e] = f2bf(xs[e] - bf2f(hs));
      }
      xh[mt][kt] = uh.v;
      xl[mt][kt] = ul.v;
    }
  }
  __syncthreads();

  floatx4 acc[2][4];
#pragma unroll
  for (int mt = 0; mt < 2; ++mt)
#pragma unroll
    for (int nt = 0; nt < 4; ++nt) acc[mt][nt] = (floatx4)(0.0f);

  // C = Xh*Wh + Xl*Wh + Xh*Wl  (lo*lo dropped).
#pragma unroll
  for (int nt = 0; nt < 4; ++nt) {
#pragma unroll
    for (int kt = 0; kt < 4; ++kt) {
      const int off = (nt * 16 + l16) * 136 + kt * 32 + quad * 8;
      const bf16x8 bh = *reinterpret_cast<const bf16x8*>(&sWh[off]);
      const bf16x8 bl = *reinterpret_cast<const bf16x8*>(&sWl[off]);
#pragma unroll
      for (int mt = 0; mt < 2; ++mt) {
        acc[mt][nt] = __builtin_amdgcn_mfma_f32_16x16x32_bf16(xh[mt][kt], bh, acc[mt][nt], 0, 0, 0);
        acc[mt][nt] = __builtin_amdgcn_mfma_f32_16x16x32_bf16(xl[mt][kt], bh, acc[mt][nt], 0, 0, 0);
        acc[mt][nt] = __builtin_amdgcn_mfma_f32_16x16x32_bf16(xh[mt][kt], bl, acc[mt][nt], 0, 0, 0);
      }
    }
  }

  // --- Epilogue: bias + convert -> sOut [128 rows][72 pad shorts] ---
  const int mat = n0 >> 7;                      // 0=Q, 1=K, 2=V
  const float* bias_p = (mat == 0) ? bq : (mat == 1) ? bk : bv;
  const int fbase = n0 & 127;
  float bias[4];
#pragma unroll
  for (int nt = 0; nt < 4; ++nt) bias[nt] = bias_p[fbase + nt * 16 + l16];

#pragma unroll
  for (int mt = 0; mt < 2; ++mt)
#pragma unroll
    for (int nt = 0; nt < 4; ++nt)
#pragma unroll
      for (int r = 0; r < 4; ++r) {
        const float val = acc[mt][nt][r] + bias[nt];
        sOut[(w * 32 + mt * 16 + quad * 4 + r) * 72 + nt * 16 + l16] =
            (mat == 2) ? f2bf(val) : f2h(val);
      }
  __syncthreads();

  // --- Store phase: 1024 x 16-B dest-contiguous chunks, 4/thread ---
  if (mat == 0) {
#pragma unroll
    for (int i = 0; i < 4; ++i) {
      const int c = i * 256 + tid, row = c >> 3, c8 = c & 7;
      *reinterpret_cast<uint4*>(Qh + (size_t)(m0b + row) * DIM + fbase + c8 * 8) =
          *reinterpret_cast<const uint4*>(&sOut[row * 72 + c8 * 8]);
    }
  } else if (mat == 1) {
#pragma unroll
    for (int i = 0; i < 4; ++i) {
      const int c = i * 256 + tid, row = c >> 3, c8 = c & 7;
      const int token = m0b + row;
      const int bK = token >> 12, j = (token & (NSEQ - 1)) >> 6, nl = token & 63;
      const int nt = nl >> 4, lk = nl & 15;
      const int feat = fbase + c8 * 8;
      const int kt = feat >> 5, qd = (feat >> 3) & 3;
      const size_t addr =
          ((((size_t)(bK * 64 + j) * 4 + nt) * 4 + kt) * 64 + qd * 16 + lk) * 8;
      *reinterpret_cast<uint4*>(KF + addr) =
          *reinterpret_cast<const uint4*>(&sOut[row * 72 + c8 * 8]);
    }
  } else {
#pragma unroll
    for (int i = 0; i < 4; ++i) {
      const int c = i * 256 + tid;
      const int d_loc = c & 63, key8 = c >> 6;
      const int d = fbase + d_loc, nt = d >> 4, lv = d & 15;
      const int k7 = key8 & 7, kt = k7 >> 2, qd = k7 & 3;
      const int token0 = m0b + key8 * 8;
      const int bV = token0 >> 12, j = (token0 & (NSEQ - 1)) >> 6;
      unsigned short tmp[8];
#pragma unroll
      for (int e = 0; e < 8; ++e) tmp[e] = sOut[(key8 * 8 + e) * 72 + d_loc];
      const size_t addr =
          ((((size_t)(bV * 64 + j) * 8 + nt) * 2 + kt) * 64 + qd * 16 + lv) * 8;
      *reinterpret_cast<uint4*>(VF + addr) = *reinterpret_cast<const uint4*>(tmp);
    }
  }
}

// ---------------------------------------------------------------------------
// Kernel 2: flash attention quarter, register-budgeted pipeline. 1024 blocks
// x 128 threads (2 waves, M=32/wave). Per iter: batched K(j) loads, QK,
// batched V(j) loads (recycling bk regs), exp/P, PV. No barriers, no spill.
// ---------------------------------------------------------------------------
__global__ __launch_bounds__(128, 2) void attn(
    const unsigned short* __restrict__ Qh, const unsigned short* __restrict__ KF,
    const unsigned short* __restrict__ VF,
    unsigned short* __restrict__ Opart, float* __restrict__ Lpart)
{
  __shared__ __align__(16) unsigned short sP[2 * 32 * 72];  // per-wave P

  const int tid  = threadIdx.x;
  const int w    = tid >> 6;
  const int lane = tid & 63;
  const int l16  = lane & 15;
  const int quad = lane >> 4;
  const int b    = blockIdx.x >> 8;
  const int sp   = (blockIdx.x >> 6) & 3;
  const int qt   = blockIdx.x & 63;
  const int q0   = qt * 64;
  const int j0   = sp * JSPL, j1 = j0 + JSPL;

  unsigned short* sPw = &sP[w * 32 * 72];

  // Q A-frags (fp16): A[m=l16][k=quad*8+e], rows w*32 + mt*16 + l16.
  f16x8 aq[2][4];
#pragma unroll
  for (int mt = 0; mt < 2; ++mt) {
    const unsigned short* qp =
        Qh + (size_t)(b * NSEQ + q0 + w * 32 + mt * 16 + l16) * DIM + quad * 8;
#pragma unroll
    for (int kt = 0; kt < 4; ++kt)
      aq[mt][kt] = *reinterpret_cast<const f16x8*>(qp + kt * 32);
  }

  floatx4 o[2][8];
#pragma unroll
  for (int mt = 0; mt < 2; ++mt)
#pragma unroll
    for (int nt = 0; nt < 8; ++nt) o[mt][nt] = (floatx4)(0.0f);
  float l_part[2][4] = {{0, 0, 0, 0}, {0, 0, 0, 0}};

  for (int j = j0; j < j1; ++j) {
    const unsigned short* kf = KF + (size_t)(b * 64 + j) * 8192 + lane * 8;
    const unsigned short* vf = VF + (size_t)(b * 64 + j) * 8192 + lane * 8;

    // Batch all 16 K-frag loads (64 VGPRs in flight).
    f16x8 bk[4][4];
#pragma unroll
    for (int nt = 0; nt < 4; ++nt)
#pragma unroll
      for (int kt = 0; kt < 4; ++kt)
        bk[nt][kt] = *reinterpret_cast<const f16x8*>(kf + nt * 2048 + kt * 512);

    // S = Q K^T (fp16).
    floatx4 s[2][4];
#pragma unroll
    for (int mt = 0; mt < 2; ++mt)
#pragma unroll
      for (int nt = 0; nt < 4; ++nt) s[mt][nt] = (floatx4)(0.0f);
#pragma unroll
    for (int nt = 0; nt < 4; ++nt)
#pragma unroll
      for (int kt = 0; kt < 4; ++kt)
#pragma unroll
        for (int mt = 0; mt < 2; ++mt)
          s[mt][nt] = __builtin_amdgcn_mfma_f32_16x16x32_f16(aq[mt][kt], bk[nt][kt], s[mt][nt], 0, 0, 0);

    // Batch all 16 V-frag loads NOW (bk dead -> regs recycle; latency hides
    // under exp + P LDS round-trip below).
    bf16x8 bv[8][2];
#pragma unroll
    for (int nt = 0; nt < 8; ++nt)
#pragma unroll
      for (int kt = 0; kt < 2; ++kt)
        bv[nt][kt] = *reinterpret_cast<const bf16x8*>(vf + nt * 1024 + kt * 512);

    // No-max softmax (logits bounded ~70 < fp32 exp limit); P bf16 (range).
#pragma unroll
    for (int mt = 0; mt < 2; ++mt)
#pragma unroll
      for (int nt = 0; nt < 4; ++nt)
#pragma unroll
        for (int r = 0; r < 4; ++r) {
          const float p = __expf(s[mt][nt][r]);
          l_part[mt][r] += p;
          sPw[(mt * 16 + quad * 4 + r) * 72 + nt * 16 + l16] = f2bf(p);
        }

    // P A-frags from wave-private LDS (no barrier).
    bf16x8 ap[2][2];
#pragma unroll
    for (int mt = 0; mt < 2; ++mt)
#pragma unroll
      for (int kt = 0; kt < 2; ++kt)
        ap[mt][kt] = *reinterpret_cast<const bf16x8*>(
            &sPw[(mt * 16 + l16) * 72 + kt * 32 + quad * 8]);

    // O += P V (bf16).
#pragma unroll
    for (int nt = 0; nt < 8; ++nt)
#pragma unroll
      for (int kt = 0; kt < 2; ++kt)
#pragma unroll
        for (int mt = 0; mt < 2; ++mt)
          o[mt][nt] = __builtin_amdgcn_mfma_f32_16x16x32_bf16(ap[mt][kt], bv[nt][kt], o[mt][nt], 0, 0, 0);
  }

  // Epilogue: reduce l over 16 cols, store normalized bf16 O-part + l-part.
#pragma unroll
  for (int mt = 0; mt < 2; ++mt)
#pragma unroll
    for (int r = 0; r < 4; ++r) {
      float l = l_part[mt][r];
      l += __shfl_xor(l, 1);
      l += __shfl_xor(l, 2);
      l += __shfl_xor(l, 4);
      l += __shfl_xor(l, 8);
      const float inv = 1.0f / l;
      const int t = q0 + w * 32 + mt * 16 + quad * 4 + r;
      const size_t ob = ((size_t)sp * TOKENS + b * NSEQ + t) * DIM;
#pragma unroll
      for (int nt = 0; nt < 8; ++nt)
        Opart[ob + nt * 16 + l16] = f2bf(o[mt][nt][r] * inv);
      if (l16 == 0) Lpart[sp * TOKENS + b * NSEQ + t] = l;
    }
}

// ---------------------------------------------------------------------------
// Kernel 3: combine quarters + residual. out = sum(l_s O_s)/sum(l_s) + x.
// ---------------------------------------------------------------------------
__global__ __launch_bounds__(256) void combine(
    const unsigned short* __restrict__ Opart, const float* __restrict__ Lpart,
    const float* __restrict__ X, float* __restrict__ Out)
{
  const int idx = blockIdx.x * 256 + threadIdx.x;
  const int T   = idx >> 4;
  const int c8  = (idx & 15) * 8;
  float ls[SPLITS], tot = 0.0f;
#pragma unroll
  for (int s = 0; s < SPLITS; ++s) { ls[s] = Lpart[s * TOKENS + T]; tot += ls[s]; }
  const float winv = 1.0f / tot;

  const size_t pa = (size_t)T * DIM + c8;
  const float4 x0 = *reinterpret_cast<const float4*>(X + pa);
  const float4 x1 = *reinterpret_cast<const float4*>(X + pa + 4);
  float os[8] = {x0.x, x0.y, x0.z, x0.w, x1.x, x1.y, x1.z, x1.w};
#pragma unroll
  for (int s = 0; s < SPLITS; ++s) {
    const float ws = ls[s] * winv;
    const uint4 u = *reinterpret_cast<const uint4*>(
        Opart + (size_t)s * TOKENS * DIM + pa);
    const unsigned uu[4] = {u.x, u.y, u.z, u.w};
#pragma unroll
    for (int e = 0; e < 4; ++e) {
      os[2 * e]     += ws * bf2f(uu[e] & 0xffff);
      os[2 * e + 1] += ws * bf2f(uu[e] >> 16);
    }
  }
  float4 o0 = {os[0], os[1], os[2], os[3]};
  float4 o1 = {os[4], os[5], os[6], os[7]};
  *reinterpret_cast<float4*>(Out + pa)     = o0;
  *reinterpret_cast<float4*>(Out + pa + 4) = o1;
}

// ---------------------------------------------------------------------------
extern "C" void kernel_launch(void* const* d_in, const int* in_sizes, int n_in,
                              void* d_out, int out_size, void* d_ws, size_t ws_size,
                              hipStream_t stream) {
  const float* X  = (const float*)d_in[0];
  const float* Wq = (const float*)d_in[1];
  const float* bq = (const float*)d_in[2];
  const float* Wk = (const float*)d_in[3];
  const float* bk = (const float*)d_in[4];
  const float* Wv = (const float*)d_in[5];
  const float* bv = (const float*)d_in[6];
  float* Out = (float*)d_out;

  const size_t MAT = (size_t)TOKENS * DIM;   // 2 M elements
  unsigned short* Qh    = (unsigned short*)d_ws;          // fp16 row-major, 4MB
  unsigned short* KF    = Qh + MAT;                       // fp16 frag, 4MB
  unsigned short* VF    = KF + MAT;                       // bf16 frag, 4MB
  unsigned short* Wth   = VF + MAT;
  unsigned short* Wtl   = Wth + 384 * 128;
  unsigned short* Opart = Wtl + 384 * 128;                // bf16, SPLITS x 4MB
  float*          Lpart = (float*)(Opart + (size_t)SPLITS * MAT);
  // total ws ~ 28.5 MB

  wprep<<<128, 384, 0, stream>>>(Wq, Wk, Wv, Wth, Wtl);
  qkv_gemm<<<dim3(6, 128), 256, 0, stream>>>(X, Wth, Wtl, bq, bk, bv,
                                             Qh, KF, VF);
  attn<<<4 * SPLITS * 64, 128, 0, stream>>>(Qh, KF, VF, Opart, Lpart);
  combine<<<(TOKENS * DIM) / (256 * 8), 256, 0, stream>>>(Opart, Lpart, X, Out);
}